// Round 15
// baseline (2187.280 us; speedup 1.0000x reference)
//
#include <hip/hip_runtime.h>
#include <math.h>

// GPNN: B=8 graphs, N=128 nodes, DV=512, DE=256, K=3, C=117.
// R15: dual-batch scan — block (s,bg) owns c-slice 16s..16s+16 for batches
// 2bg and 2bg+1. Weights (wihL/w2L) shared; ONE barrier/atomic-drain/poll per
// step serves both batches. Protocol/ordering per batch identical to R14.

#define NB 8
#define NN 128
#define DVV 512
#define DEE 256
#define NCC 117
#define SB 16
#define GISLOT 12288   // floats per gi slot (8 batches x 1536)

typedef __attribute__((ext_vector_type(8))) short short8;
typedef __attribute__((ext_vector_type(4))) float f32x4;

__device__ __forceinline__ float sigmf(float x) {
  x = fminf(fmaxf(x, -30.f), 30.f);
  return 1.0f / (1.0f + __expf(-x));
}
__device__ __forceinline__ float tanhf_fast(float x) {
  x = fminf(fmaxf(x, -15.f), 15.f);
  float e = __expf(2.0f * x);
  return (e - 1.0f) / (e + 1.0f);
}
__device__ __forceinline__ unsigned short f2bf(float f) {
  union { float f; unsigned u; } v; v.f = f;
  unsigned u = v.u + 0x7FFFu + ((v.u >> 16) & 1u);
  return (unsigned short)(u >> 16);
}
__device__ __forceinline__ float bfu(unsigned short u) {
  union { unsigned u; float f; } v; v.u = ((unsigned)u) << 16; return v.f;
}

// ---------------- h init (+ hb bf16) ----------------
__global__ __launch_bounds__(256) void k_copy(const float* __restrict__ src, float* __restrict__ dst,
                                              unsigned short* __restrict__ hb) {
  int i = blockIdx.x * 256 + threadIdx.x;
  float4 v = ((const float4*)src)[i];
  ((float4*)dst)[i] = v;
  unsigned long long pk = (unsigned long long)f2bf(v.x) | ((unsigned long long)f2bf(v.y) << 16)
                        | ((unsigned long long)f2bf(v.z) << 32) | ((unsigned long long)f2bf(v.w) << 48);
  *(unsigned long long*)&hb[i * 4] = pk;
}

// ---------------- W3 -> bf16 (once) ----------------
__global__ __launch_bounds__(256) void k_cvtw(const float* __restrict__ w_msg,
                                              unsigned short* __restrict__ w3b) {
  int idx = blockIdx.x * 256 + threadIdx.x;      // 65536
  int r = idx >> 8, c = idx & 255;
  w3b[idx] = f2bf(w_msg[(size_t)r * 1280 + 1024 + c]);
}

// ---------------- ai/aj ----------------
__global__ __launch_bounds__(128) void k_av(const float* __restrict__ h, const float* __restrict__ w_link,
                                            float* __restrict__ av) {
  int b = blockIdx.x >> 7, n = blockIdx.x & 127;
  int lane = threadIdx.x & 63, half = threadIdx.x >> 6;
  const float* hc = h + (size_t)((b << 7) + n) * DVV;
  const float* w = w_link + half * DVV;
  float acc = 0.f;
#pragma unroll
  for (int t = 0; t < 8; ++t) { int d = lane + (t << 6); acc += w[d] * hc[d]; }
#pragma unroll
  for (int off = 32; off; off >>= 1) acc += __shfl_down(acc, off);
  if (lane == 0) av[(b << 8) + half * NN + n] = acc;
}

// ---------------- per-row: adj (fused) + P = W3 @ e_row via bf16 MFMA; e bf16 [c][j] ----------------
template <int FIRST>
__global__ __launch_bounds__(256) void k_plogit_mfma(
    const float* edge, const unsigned short* eP16in, const unsigned short* __restrict__ w3b,
    const float* __restrict__ w_link, const float* __restrict__ av,
    const float* __restrict__ b_link, unsigned short* eP16out, float* __restrict__ adj_out) {
  int b = blockIdx.x >> 7, i = blockIdx.x & 127;
  __shared__ unsigned short eL[128 * 264];       // [j][c], 528B rows (16B-aligned)
  int tid = threadIdx.x;

  if (FIRST) {
    const float* s0 = edge + (size_t)(b * NN + i) * NN * DEE;
    for (int l = tid; l < 4096; l += 256) {
      int j = l >> 5, c0 = (l & 31) * 8;
      float4 v0 = *(const float4*)&s0[(size_t)j * DEE + c0];
      float4 v1 = *(const float4*)&s0[(size_t)j * DEE + c0 + 4];
      unsigned long long p0 = (unsigned long long)f2bf(v0.x) | ((unsigned long long)f2bf(v0.y) << 16)
                            | ((unsigned long long)f2bf(v0.z) << 32) | ((unsigned long long)f2bf(v0.w) << 48);
      unsigned long long p1 = (unsigned long long)f2bf(v1.x) | ((unsigned long long)f2bf(v1.y) << 16)
                            | ((unsigned long long)f2bf(v1.z) << 32) | ((unsigned long long)f2bf(v1.w) << 48);
      *(unsigned long long*)&eL[j * 264 + c0] = p0;
      *(unsigned long long*)&eL[j * 264 + c0 + 4] = p1;
    }
  } else {
    const unsigned short* s0 = eP16in + (size_t)(b * NN + i) * DEE * NN;
#pragma unroll
    for (int t = 0; t < 2; ++t) {
      int blk = tid + t * 256;                   // 512 8x8 blocks
      int c0 = (blk >> 4) * 8, j0 = (blk & 15) * 8;
      short8 rows[8];
#pragma unroll
      for (int cc = 0; cc < 8; ++cc)
        rows[cc] = *(const short8*)&s0[(size_t)(c0 + cc) * NN + j0];
#pragma unroll
      for (int jj = 0; jj < 8; ++jj) {
        short8 o;
#pragma unroll
        for (int cc = 0; cc < 8; ++cc) o[cc] = rows[cc][jj];
        *(short8*)&eL[(j0 + jj) * 264 + c0] = o;
      }
    }
  }
  __syncthreads();

  // logitE per j
  float accLE = 0.f;
  if (tid < NN) {
    const unsigned short* row = &eL[tid * 264];
    for (int c = 0; c < DEE; ++c) accLE += w_link[1024 + c] * bfu(row[c]);
  }

  // MFMA main loop
  const int w = tid >> 6, l = tid & 63;
  const int lm = l & 15, lg = l >> 4;
  f32x4 acc[4][8];
#pragma unroll
  for (int a = 0; a < 4; ++a)
#pragma unroll
    for (int jt = 0; jt < 8; ++jt) acc[a][jt] = (f32x4){0.f, 0.f, 0.f, 0.f};

#pragma unroll
  for (int kk = 0; kk < 8; ++kk) {
    short8 afr[4];
#pragma unroll
    for (int a = 0; a < 4; ++a)
      afr[a] = *(const short8*)&w3b[(size_t)(64 * w + 16 * a + lm) * 256 + 32 * kk + 8 * lg];
#pragma unroll
    for (int jt = 0; jt < 8; ++jt) {
      short8 bfr = *(const short8*)&eL[(16 * jt + lm) * 264 + 32 * kk + 8 * lg];
#pragma unroll
      for (int a = 0; a < 4; ++a)
        acc[a][jt] = __builtin_amdgcn_mfma_f32_16x16x32_bf16(afr[a], bfr, acc[a][jt], 0, 0, 0);
    }
  }

  // epilogue: P bf16 [c][j]
  unsigned short* Pout = eP16out + (size_t)(b * NN + i) * DEE * NN;
#pragma unroll
  for (int a = 0; a < 4; ++a) {
    int rbase = 64 * w + 16 * a + 4 * lg;
#pragma unroll
    for (int jt = 0; jt < 8; ++jt) {
      int j = 16 * jt + lm;
#pragma unroll
      for (int q = 0; q < 4; ++q)
        Pout[(size_t)(rbase + q) * NN + j] = f2bf(acc[a][jt][q]);
    }
  }
  if (tid < NN) {
    float x = av[(b << 8) + NN + i] + av[(b << 8) + tid] + accLE + b_link[0];
    adj_out[((size_t)b * NN + i) * NN + tid] = sigmf(x);
  }
}

// ---------------- merged W@h kernel (R9 scalar, PROVEN) ----------------
__global__ __launch_bounds__(256) void k_wh3(const float* __restrict__ w_hh, const float* __restrict__ w_msg,
                                             const float* __restrict__ b_hh, const float* __restrict__ b_msg,
                                             const float* __restrict__ h, float* __restrict__ GHo,
                                             float* __restrict__ Uo, float* __restrict__ Go) {
  int bx = blockIdx.x, b = blockIdx.y;
  const float* W; const float* bias; float* out; int ldw, R, r0;
  if (bx < 96)       { W = w_hh;        ldw = 512;  R = 1536; bias = b_hh;   out = GHo; r0 = bx * 16; }
  else if (bx < 112) { W = w_msg;       ldw = 1280; R = 256;  bias = b_msg;  out = Uo;  r0 = (bx - 96) * 16; }
  else               { W = w_msg + 512; ldw = 1280; R = 256;  bias = nullptr; out = Go; r0 = (bx - 112) * 16; }
  __shared__ float hT[128][129];
  __shared__ float wT[16][129];
  __shared__ float outT[16][129];
  int tid = threadIdx.x;
  int n = tid & 127, rr = tid >> 7;
  float acc8[8] = {0, 0, 0, 0, 0, 0, 0, 0};
  for (int dc = 0; dc < DVV; dc += 128) {
    if (dc) __syncthreads();
    for (int l = tid * 4; l < 16384; l += 1024) {
      int nn = l >> 7, d = l & 127;
      float4 v = *(const float4*)&h[((size_t)(b << 7) + nn) * DVV + dc + d];
      hT[d + 0][nn] = v.x; hT[d + 1][nn] = v.y; hT[d + 2][nn] = v.z; hT[d + 3][nn] = v.w;
    }
    for (int l = tid; l < 2048; l += 256) {
      int r = l >> 7, d = l & 127;
      wT[r][d] = W[(size_t)(r0 + r) * ldw + dc + d];
    }
    __syncthreads();
    for (int d = 0; d < 128; ++d) {
      float hval = hT[d][n];
#pragma unroll
      for (int r8 = 0; r8 < 8; ++r8) acc8[r8] += wT[rr * 8 + r8][d] * hval;
    }
  }
#pragma unroll
  for (int r8 = 0; r8 < 8; ++r8) {
    int r = rr * 8 + r8;
    outT[r][n] = acc8[r8] + (bias ? bias[r0 + r] : 0.0f);
  }
  __syncthreads();
  int n2 = tid >> 1, q = tid & 1;
  size_t base = ((size_t)(b << 7) + n2) * R + r0 + q * 8;
  float4 o0; o0.x = outT[q * 8 + 0][n2]; o0.y = outT[q * 8 + 1][n2]; o0.z = outT[q * 8 + 2][n2]; o0.w = outT[q * 8 + 3][n2];
  float4 o1; o1.x = outT[q * 8 + 4][n2]; o1.y = outT[q * 8 + 5][n2]; o1.z = outT[q * 8 + 6][n2]; o1.w = outT[q * 8 + 7][n2];
  *(float4*)&out[base] = o0;
  *(float4*)&out[base + 4] = o1;
}

// ---------------- dual-batch distributed scan ----------------
template <int WRITE_E>
__global__ __launch_bounds__(256) void k_scan15(
    unsigned short* eP16, const float* __restrict__ adj, const float* __restrict__ GH,
    const float* __restrict__ U, const float* __restrict__ Gini, float* __restrict__ h,
    unsigned short* __restrict__ hb, const float* __restrict__ w_ih,
    const float* __restrict__ b_ih, const float* __restrict__ w_msg,
    float* __restrict__ gi, unsigned* __restrict__ flags, int kround) {
  const int s = blockIdx.x, bg = blockIdx.y, tid = threadIdx.x;
  const int b0 = 2 * bg, b1 = 2 * bg + 1;
  __shared__ float wihL[16 * 1540];              // 98.6 KB (shared by both batches)
  __shared__ __align__(16) float w2L[16 * 520];  // 33.3 KB (shared)
  __shared__ __align__(16) float GL0[16 * 132];
  __shared__ __align__(16) float GL1[16 * 132];
  __shared__ float hnL0[DVV];
  __shared__ float hnL1[DVV];
  __shared__ float msL0[16];
  __shared__ float msL1[16];

  for (int l = tid; l < 1536 * 16; l += 256) {
    int r = l >> 4, c = l & 15;
    wihL[c * 1540 + r] = w_ih[(size_t)r * 256 + 16 * s + c];
  }
  for (int l = tid; l < 16 * 128; l += 256) {
    int c = l >> 7, d4 = (l & 127) * 4;
    *(float4*)&w2L[c * 520 + d4] = *(const float4*)&w_msg[(size_t)(16 * s + c) * 1280 + 512 + d4];
  }
  for (int l = tid; l < 2048; l += 256) {
    int c = l & 15, j = l >> 4;
    GL0[c * 132 + j] = Gini[((size_t)b0 * NN + j) * DEE + 16 * s + c];
    GL1[c * 132 + j] = Gini[((size_t)b1 * NN + j) * DEE + 16 * s + c];
  }
  float bi0 = b_ih[tid], bi1 = b_ih[tid + 256];
  float bi2 = b_ih[512 + tid], bi3 = b_ih[768 + tid];
  float bi4 = b_ih[1024 + tid], bi5 = b_ih[1280 + tid];

  const int c_loc = tid >> 4, jg = tid & 15, j0 = jg << 3;

  short8 Pv0, Pv1; float4 A00, A01, A10, A11; float uu0, uu1;
  float hv00, hv01, ghr00, ghr01, ghz00, ghz01, ghn00, ghn01;
  float hv10, hv11, ghr10, ghr11, ghz10, ghz11, ghn10, ghn11;
  {
    size_t rE = ((size_t)(b0 * NN + 0) * DEE + 16 * s + c_loc) * NN + j0;
    Pv0 = *(const short8*)&eP16[rE];
    size_t rA = (size_t)(b0 * NN + 0) * NN + j0;
    A00 = *(const float4*)&adj[rA]; A01 = *(const float4*)&adj[rA + 4];
    uu0 = U[(size_t)(b0 * NN + 0) * DEE + 16 * s + c_loc];
    size_t rH = (size_t)(b0 * NN + 0) * DVV;
    hv00 = h[rH + tid]; hv01 = h[rH + tid + 256];
    size_t rG = (size_t)(b0 * NN + 0) * 1536;
    ghr00 = GH[rG + tid]; ghr01 = GH[rG + tid + 256];
    ghz00 = GH[rG + 512 + tid]; ghz01 = GH[rG + 768 + tid];
    ghn00 = GH[rG + 1024 + tid]; ghn01 = GH[rG + 1280 + tid];
    rE = ((size_t)(b1 * NN + 0) * DEE + 16 * s + c_loc) * NN + j0;
    Pv1 = *(const short8*)&eP16[rE];
    rA = (size_t)(b1 * NN + 0) * NN + j0;
    A10 = *(const float4*)&adj[rA]; A11 = *(const float4*)&adj[rA + 4];
    uu1 = U[(size_t)(b1 * NN + 0) * DEE + 16 * s + c_loc];
    rH = (size_t)(b1 * NN + 0) * DVV;
    hv10 = h[rH + tid]; hv11 = h[rH + tid + 256];
    rG = (size_t)(b1 * NN + 0) * 1536;
    ghr10 = GH[rG + tid]; ghr11 = GH[rG + tid + 256];
    ghz10 = GH[rG + 512 + tid]; ghz11 = GH[rG + 768 + tid];
    ghn10 = GH[rG + 1024 + tid]; ghn11 = GH[rG + 1280 + tid];
  }

  for (int i = 0; i < NN; ++i) {
    int g = kround * NN + i;
    float* giA0 = gi + (size_t)(g % 3) * GISLOT + (size_t)b0 * 1536;
    float* giZ0 = gi + (size_t)((g + 1) % 3) * GISLOT + (size_t)b0 * 1536;
    float* giA1 = gi + (size_t)(g % 3) * GISLOT + (size_t)b1 * 1536;
    float* giZ1 = gi + (size_t)((g + 1) % 3) * GISLOT + (size_t)b1 * 1536;
    __syncthreads();   // (1)

    // ---- Phase A both batches ----
    float acc0, acc1;
    {
      const float* gl = &GL0[c_loc * 132 + j0];
      float4 g0 = *(const float4*)&gl[0];
      float4 g1 = *(const float4*)&gl[4];
      float m0 = fmaxf(uu0 + g0.x + bfu((unsigned short)Pv0[0]), 0.f);
      float m1 = fmaxf(uu0 + g0.y + bfu((unsigned short)Pv0[1]), 0.f);
      float m2 = fmaxf(uu0 + g0.z + bfu((unsigned short)Pv0[2]), 0.f);
      float m3 = fmaxf(uu0 + g0.w + bfu((unsigned short)Pv0[3]), 0.f);
      float m4 = fmaxf(uu0 + g1.x + bfu((unsigned short)Pv0[4]), 0.f);
      float m5 = fmaxf(uu0 + g1.y + bfu((unsigned short)Pv0[5]), 0.f);
      float m6 = fmaxf(uu0 + g1.z + bfu((unsigned short)Pv0[6]), 0.f);
      float m7 = fmaxf(uu0 + g1.w + bfu((unsigned short)Pv0[7]), 0.f);
      acc0 = A00.x * m0 + A00.y * m1 + A00.z * m2 + A00.w * m3
           + A01.x * m4 + A01.y * m5 + A01.z * m6 + A01.w * m7;
      if (WRITE_E) {
        size_t rE = ((size_t)(b0 * NN + i) * DEE + 16 * s + c_loc) * NN + j0;
        short8 mw;
        mw[0] = (short)f2bf(m0); mw[1] = (short)f2bf(m1); mw[2] = (short)f2bf(m2); mw[3] = (short)f2bf(m3);
        mw[4] = (short)f2bf(m4); mw[5] = (short)f2bf(m5); mw[6] = (short)f2bf(m6); mw[7] = (short)f2bf(m7);
        *(short8*)&eP16[rE] = mw;
      }
    }
    {
      const float* gl = &GL1[c_loc * 132 + j0];
      float4 g0 = *(const float4*)&gl[0];
      float4 g1 = *(const float4*)&gl[4];
      float m0 = fmaxf(uu1 + g0.x + bfu((unsigned short)Pv1[0]), 0.f);
      float m1 = fmaxf(uu1 + g0.y + bfu((unsigned short)Pv1[1]), 0.f);
      float m2 = fmaxf(uu1 + g0.z + bfu((unsigned short)Pv1[2]), 0.f);
      float m3 = fmaxf(uu1 + g0.w + bfu((unsigned short)Pv1[3]), 0.f);
      float m4 = fmaxf(uu1 + g1.x + bfu((unsigned short)Pv1[4]), 0.f);
      float m5 = fmaxf(uu1 + g1.y + bfu((unsigned short)Pv1[5]), 0.f);
      float m6 = fmaxf(uu1 + g1.z + bfu((unsigned short)Pv1[6]), 0.f);
      float m7 = fmaxf(uu1 + g1.w + bfu((unsigned short)Pv1[7]), 0.f);
      acc1 = A10.x * m0 + A10.y * m1 + A10.z * m2 + A10.w * m3
           + A11.x * m4 + A11.y * m5 + A11.z * m6 + A11.w * m7;
      if (WRITE_E) {
        size_t rE = ((size_t)(b1 * NN + i) * DEE + 16 * s + c_loc) * NN + j0;
        short8 mw;
        mw[0] = (short)f2bf(m0); mw[1] = (short)f2bf(m1); mw[2] = (short)f2bf(m2); mw[3] = (short)f2bf(m3);
        mw[4] = (short)f2bf(m4); mw[5] = (short)f2bf(m5); mw[6] = (short)f2bf(m6); mw[7] = (short)f2bf(m7);
        *(short8*)&eP16[rE] = mw;
      }
    }
    acc0 += __shfl_down(acc0, 8); acc1 += __shfl_down(acc1, 8);
    acc0 += __shfl_down(acc0, 4); acc1 += __shfl_down(acc1, 4);
    acc0 += __shfl_down(acc0, 2); acc1 += __shfl_down(acc1, 2);
    acc0 += __shfl_down(acc0, 1); acc1 += __shfl_down(acc1, 1);
    if (jg == 0) { msL0[c_loc] = acc0; msL1[c_loc] = acc1; }
    __syncthreads();   // (2)

    // ---- Phase B both batches (weight LDS reads shared) ----
    {
      float ms0[16], ms1[16];
#pragma unroll
      for (int c = 0; c < 16; ++c) { ms0[c] = msL0[c]; ms1[c] = msL1[c]; }
#pragma unroll
      for (int u = 0; u < 6; ++u) {
        int r = tid + (u << 8);
        float pa0 = 0.f, pa1 = 0.f;
#pragma unroll
        for (int c = 0; c < 16; ++c) {
          float wv = wihL[c * 1540 + r];
          pa0 += wv * ms0[c]; pa1 += wv * ms1[c];
        }
        (void)__hip_atomic_fetch_add(&giA0[r], pa0, __ATOMIC_RELAXED, __HIP_MEMORY_SCOPE_SYSTEM);
        (void)__hip_atomic_fetch_add(&giA1[r], pa1, __ATOMIC_RELAXED, __HIP_MEMORY_SCOPE_SYSTEM);
      }
      if (tid < 96) {
        __hip_atomic_store(&giZ0[96 * s + tid], 0.f, __ATOMIC_RELAXED, __HIP_MEMORY_SCOPE_SYSTEM);
        __hip_atomic_store(&giZ1[96 * s + tid], 0.f, __ATOMIC_RELAXED, __HIP_MEMORY_SCOPE_SYSTEM);
      }
    }

    // ---- ONE barrier for both batches ----
    unsigned tgt = (unsigned)(g + 1);
    __syncthreads();   // (3) drains all atomics + zero stores
    if (tid == 0)
      __hip_atomic_store(&flags[(((bg << 4) + s) << 5)], tgt, __ATOMIC_RELAXED,
                         __HIP_MEMORY_SCOPE_SYSTEM);
    // prefetch i+1 for BOTH batches (overlaps poll + gi loads + GRUs)
    float t_hv00, t_hv01, t_ghr00, t_ghr01, t_ghz00, t_ghz01, t_ghn00, t_ghn01;
    float t_hv10, t_hv11, t_ghr10, t_ghr11, t_ghz10, t_ghz11, t_ghn10, t_ghn11;
    {
      int in = (i < NN - 1) ? i + 1 : NN - 1;
      size_t rE = ((size_t)(b0 * NN + in) * DEE + 16 * s + c_loc) * NN + j0;
      Pv0 = *(const short8*)&eP16[rE];
      size_t rA = (size_t)(b0 * NN + in) * NN + j0;
      A00 = *(const float4*)&adj[rA]; A01 = *(const float4*)&adj[rA + 4];
      uu0 = U[(size_t)(b0 * NN + in) * DEE + 16 * s + c_loc];
      size_t rH = (size_t)(b0 * NN + in) * DVV;
      t_hv00 = h[rH + tid]; t_hv01 = h[rH + tid + 256];
      size_t rG = (size_t)(b0 * NN + in) * 1536;
      t_ghr00 = GH[rG + tid]; t_ghr01 = GH[rG + tid + 256];
      t_ghz00 = GH[rG + 512 + tid]; t_ghz01 = GH[rG + 768 + tid];
      t_ghn00 = GH[rG + 1024 + tid]; t_ghn01 = GH[rG + 1280 + tid];
      rE = ((size_t)(b1 * NN + in) * DEE + 16 * s + c_loc) * NN + j0;
      Pv1 = *(const short8*)&eP16[rE];
      rA = (size_t)(b1 * NN + in) * NN + j0;
      A10 = *(const float4*)&adj[rA]; A11 = *(const float4*)&adj[rA + 4];
      uu1 = U[(size_t)(b1 * NN + in) * DEE + 16 * s + c_loc];
      rH = (size_t)(b1 * NN + in) * DVV;
      t_hv10 = h[rH + tid]; t_hv11 = h[rH + tid + 256];
      rG = (size_t)(b1 * NN + in) * 1536;
      t_ghr10 = GH[rG + tid]; t_ghr11 = GH[rG + tid + 256];
      t_ghz10 = GH[rG + 512 + tid]; t_ghz11 = GH[rG + 768 + tid];
      t_ghn10 = GH[rG + 1024 + tid]; t_ghn11 = GH[rG + 1280 + tid];
    }
    if (tid < 64) {
      unsigned* fp = &flags[(((bg << 4) + (tid & 15)) << 5)];
      for (;;) {
        unsigned v = __hip_atomic_load(fp, __ATOMIC_RELAXED, __HIP_MEMORY_SCOPE_SYSTEM);
        if (!__any(v < tgt)) break;
        __builtin_amdgcn_s_sleep(1);
      }
    }
    __syncthreads();   // (4)

    // ---- GRU both batches: issue all 12 gi loads, then compute ----
    {
      float q00 = __hip_atomic_load(&giA0[tid],        __ATOMIC_RELAXED, __HIP_MEMORY_SCOPE_SYSTEM);
      float q01 = __hip_atomic_load(&giA0[tid + 256],  __ATOMIC_RELAXED, __HIP_MEMORY_SCOPE_SYSTEM);
      float q02 = __hip_atomic_load(&giA0[512 + tid],  __ATOMIC_RELAXED, __HIP_MEMORY_SCOPE_SYSTEM);
      float q03 = __hip_atomic_load(&giA0[768 + tid],  __ATOMIC_RELAXED, __HIP_MEMORY_SCOPE_SYSTEM);
      float q04 = __hip_atomic_load(&giA0[1024 + tid], __ATOMIC_RELAXED, __HIP_MEMORY_SCOPE_SYSTEM);
      float q05 = __hip_atomic_load(&giA0[1280 + tid], __ATOMIC_RELAXED, __HIP_MEMORY_SCOPE_SYSTEM);
      float q10 = __hip_atomic_load(&giA1[tid],        __ATOMIC_RELAXED, __HIP_MEMORY_SCOPE_SYSTEM);
      float q11 = __hip_atomic_load(&giA1[tid + 256],  __ATOMIC_RELAXED, __HIP_MEMORY_SCOPE_SYSTEM);
      float q12 = __hip_atomic_load(&giA1[512 + tid],  __ATOMIC_RELAXED, __HIP_MEMORY_SCOPE_SYSTEM);
      float q13 = __hip_atomic_load(&giA1[768 + tid],  __ATOMIC_RELAXED, __HIP_MEMORY_SCOPE_SYSTEM);
      float q14 = __hip_atomic_load(&giA1[1024 + tid], __ATOMIC_RELAXED, __HIP_MEMORY_SCOPE_SYSTEM);
      float q15 = __hip_atomic_load(&giA1[1280 + tid], __ATOMIC_RELAXED, __HIP_MEMORY_SCOPE_SYSTEM);
      {
        float rg0 = sigmf(bi0 + q00 + ghr00), rg1 = sigmf(bi1 + q01 + ghr01);
        float z0 = sigmf(bi2 + q02 + ghz00),  z1 = sigmf(bi3 + q03 + ghz01);
        float nv0 = tanhf_fast(bi4 + q04 + rg0 * ghn00);
        float nv1 = tanhf_fast(bi5 + q05 + rg1 * ghn01);
        float hn0 = (1.f - z0) * nv0 + z0 * hv00;
        float hn1 = (1.f - z1) * nv1 + z1 * hv01;
        hnL0[tid] = hn0; hnL0[tid + 256] = hn1;
        size_t rH = (size_t)(b0 * NN + i) * DVV;
        if ((tid >> 5) == s)         { h[rH + tid] = hn0;       hb[rH + tid] = f2bf(hn0); }
        if (((tid + 256) >> 5) == s) { h[rH + tid + 256] = hn1; hb[rH + tid + 256] = f2bf(hn1); }
      }
      {
        float rg0 = sigmf(bi0 + q10 + ghr10), rg1 = sigmf(bi1 + q11 + ghr11);
        float z0 = sigmf(bi2 + q12 + ghz10),  z1 = sigmf(bi3 + q13 + ghz11);
        float nv0 = tanhf_fast(bi4 + q14 + rg0 * ghn10);
        float nv1 = tanhf_fast(bi5 + q15 + rg1 * ghn11);
        float hn0 = (1.f - z0) * nv0 + z0 * hv10;
        float hn1 = (1.f - z1) * nv1 + z1 * hv11;
        hnL1[tid] = hn0; hnL1[tid + 256] = hn1;
        size_t rH = (size_t)(b1 * NN + i) * DVV;
        if ((tid >> 5) == s)         { h[rH + tid] = hn0;       hb[rH + tid] = f2bf(hn0); }
        if (((tid + 256) >> 5) == s) { h[rH + tid + 256] = hn1; hb[rH + tid + 256] = f2bf(hn1); }
      }
    }
    // commit prefetched h/GH
    hv00 = t_hv00; hv01 = t_hv01; ghr00 = t_ghr00; ghr01 = t_ghr01;
    ghz00 = t_ghz00; ghz01 = t_ghz01; ghn00 = t_ghn00; ghn01 = t_ghn01;
    hv10 = t_hv10; hv11 = t_hv11; ghr10 = t_ghr10; ghr11 = t_ghr11;
    ghz10 = t_ghz10; ghz11 = t_ghz11; ghn10 = t_ghn10; ghn11 = t_ghn11;
    __syncthreads();   // (5)

    // ---- Phase C both batches (w2L reads shared) ----
    {
      int cw = tid >> 4, dg = tid & 15;
      float a0 = 0.f, a1 = 0.f;
#pragma unroll
      for (int it = 0; it < 32; ++it) {
        int d = dg + (it << 4);
        float wv = w2L[cw * 520 + d];
        a0 += wv * hnL0[d];
        a1 += wv * hnL1[d];
      }
      a0 += __shfl_down(a0, 8); a1 += __shfl_down(a1, 8);
      a0 += __shfl_down(a0, 4); a1 += __shfl_down(a1, 4);
      a0 += __shfl_down(a0, 2); a1 += __shfl_down(a1, 2);
      a0 += __shfl_down(a0, 1); a1 += __shfl_down(a1, 1);
      if (dg == 0) { GL0[cw * 132 + i] = a0; GL1[cw * 132 + i] = a1; }
    }
  }
}

// ---------------- labels ----------------
__global__ __launch_bounds__(128) void k_labels(const float* __restrict__ h, const float* __restrict__ w_ro,
                                                const float* __restrict__ b_ro, float* __restrict__ out) {
  int b = blockIdx.x >> 7, n = blockIdx.x & 127;
  __shared__ __align__(16) float hr[512];
  int tid = threadIdx.x;
  *(float4*)&hr[tid * 4] = *(const float4*)&h[(size_t)((b << 7) + n) * DVV + tid * 4];
  __syncthreads();
  if (tid < NCC) {
    const float* w = w_ro + (size_t)tid * DVV;
    float acc = b_ro[tid];
    for (int d = 0; d < DVV; d += 4) {
      float4 wv = *(const float4*)&w[d];
      acc += wv.x * hr[d] + wv.y * hr[d + 1] + wv.z * hr[d + 2] + wv.w * hr[d + 3];
    }
    out[(size_t)((b << 7) + n) * NCC + tid] = acc;
  }
}

extern "C" void kernel_launch(void* const* d_in, const int* in_sizes, int n_in,
                              void* d_out, int out_size, void* d_ws, size_t ws_size,
                              hipStream_t stream) {
  const float* edge   = (const float*)d_in[0];
  const float* node   = (const float*)d_in[1];
  const float* w_link = (const float*)d_in[6];
  const float* b_link = (const float*)d_in[7];
  const float* w_msg  = (const float*)d_in[8];
  const float* b_msg  = (const float*)d_in[9];
  const float* w_ih   = (const float*)d_in[10];
  const float* w_hh   = (const float*)d_in[11];
  const float* b_ih   = (const float*)d_in[12];
  const float* b_hh   = (const float*)d_in[13];
  const float* w_ro   = (const float*)d_in[14];
  const float* b_ro   = (const float*)d_in[15];
  float* out = (float*)d_out;
  float* ws  = (float*)d_ws;

  unsigned short* eP16 = (unsigned short*)ws;               // 33,554,432 ushorts
  unsigned short* hb   = (unsigned short*)(ws + 21000000);  //   524,288 ushorts
  float* h_buf  = ws + 33554432ull;        //    524,288  (B,N,DV)
  float* GH_buf = h_buf + 524288;          //  1,572,864  (B,N,1536)
  float* U_buf  = GH_buf + 1572864;        //    262,144  (B,N,256)
  float* G_buf  = U_buf + 262144;          //    262,144  (B,N,256)
  float* lE_buf = G_buf + 262144;          //    131,072  (reused: w3b)
  float* av_buf = lE_buf + 131072;         //      2,048  (B,2,N)
  float* gi_buf = av_buf + 2048;           //     36,864  (3 slots x B x 1536)
  unsigned* flags = (unsigned*)(gi_buf + 3 * GISLOT);  // 4096 u32
  unsigned short* w3b = (unsigned short*)lE_buf;
  size_t need_bytes = 36710304ull * 4ull;
  if (ws_size < need_bytes) return;

  hipMemsetAsync(gi_buf, 0, (3 * GISLOT + 4096) * sizeof(float), stream);
  k_copy<<<512, 256, 0, stream>>>(node, h_buf, hb);
  k_cvtw<<<256, 256, 0, stream>>>(w_msg, w3b);

  for (int k = 0; k < 3; ++k) {
    k_av<<<1024, 128, 0, stream>>>(h_buf, w_link, av_buf);
    if (k == 0) k_plogit_mfma<1><<<1024, 256, 0, stream>>>(edge, eP16, w3b, w_link, av_buf, b_link, eP16, out);
    else        k_plogit_mfma<0><<<1024, 256, 0, stream>>>(edge, eP16, w3b, w_link, av_buf, b_link, eP16, out);
    k_wh3<<<dim3(128, 8), 256, 0, stream>>>(w_hh, w_msg, b_hh, b_msg, h_buf, GH_buf, U_buf, G_buf);
    if (k < 2) k_scan15<1><<<dim3(SB, NB / 2), 256, 0, stream>>>(eP16, out, GH_buf, U_buf, G_buf, h_buf, hb,
                                                                 w_ih, b_ih, w_msg, gi_buf, flags, k);
    else       k_scan15<0><<<dim3(SB, NB / 2), 256, 0, stream>>>(eP16, out, GH_buf, U_buf, G_buf, h_buf, hb,
                                                                 w_ih, b_ih, w_msg, gi_buf, flags, k);
  }
  k_labels<<<1024, 128, 0, stream>>>(h_buf, w_ro, b_ro, out + 131072);
}

// Round 17
// 1876.080 us; speedup vs baseline: 1.1659x; 1.1659x over previous
//
#include <hip/hip_runtime.h>
#include <math.h>

// GPNN: B=8 graphs, N=128 nodes, DV=512, DE=256, K=3, C=117.
// R17 = R14 verbatim (best passing: 1874us). R15 (dual-batch) and R16
// (poll/prefetch/remap micro-opts) both regressed or failed; the scan's
// 1-barrier protocol is at its verifiable floor (~3.3us/step = atomic drain
// + flag skew + gi reads + compute on a 384-step serial chain).

#define NB 8
#define NN 128
#define DVV 512
#define DEE 256
#define NCC 117
#define SB 16
#define GISLOT 12288   // floats per gi slot (8 batches x 1536)

typedef __attribute__((ext_vector_type(8))) short short8;
typedef __attribute__((ext_vector_type(4))) float f32x4;

__device__ __forceinline__ float sigmf(float x) {
  x = fminf(fmaxf(x, -30.f), 30.f);
  return 1.0f / (1.0f + __expf(-x));
}
__device__ __forceinline__ float tanhf_fast(float x) {
  x = fminf(fmaxf(x, -15.f), 15.f);
  float e = __expf(2.0f * x);
  return (e - 1.0f) / (e + 1.0f);
}
__device__ __forceinline__ unsigned short f2bf(float f) {
  union { float f; unsigned u; } v; v.f = f;
  unsigned u = v.u + 0x7FFFu + ((v.u >> 16) & 1u);
  return (unsigned short)(u >> 16);
}
__device__ __forceinline__ float bfu(unsigned short u) {
  union { unsigned u; float f; } v; v.u = ((unsigned)u) << 16; return v.f;
}

// ---------------- h init (+ hb bf16) ----------------
__global__ __launch_bounds__(256) void k_copy(const float* __restrict__ src, float* __restrict__ dst,
                                              unsigned short* __restrict__ hb) {
  int i = blockIdx.x * 256 + threadIdx.x;
  float4 v = ((const float4*)src)[i];
  ((float4*)dst)[i] = v;
  unsigned long long pk = (unsigned long long)f2bf(v.x) | ((unsigned long long)f2bf(v.y) << 16)
                        | ((unsigned long long)f2bf(v.z) << 32) | ((unsigned long long)f2bf(v.w) << 48);
  *(unsigned long long*)&hb[i * 4] = pk;
}

// ---------------- W3 -> bf16 (once) ----------------
__global__ __launch_bounds__(256) void k_cvtw(const float* __restrict__ w_msg,
                                              unsigned short* __restrict__ w3b) {
  int idx = blockIdx.x * 256 + threadIdx.x;      // 65536
  int r = idx >> 8, c = idx & 255;
  w3b[idx] = f2bf(w_msg[(size_t)r * 1280 + 1024 + c]);
}

// ---------------- ai/aj ----------------
__global__ __launch_bounds__(128) void k_av(const float* __restrict__ h, const float* __restrict__ w_link,
                                            float* __restrict__ av) {
  int b = blockIdx.x >> 7, n = blockIdx.x & 127;
  int lane = threadIdx.x & 63, half = threadIdx.x >> 6;
  const float* hc = h + (size_t)((b << 7) + n) * DVV;
  const float* w = w_link + half * DVV;
  float acc = 0.f;
#pragma unroll
  for (int t = 0; t < 8; ++t) { int d = lane + (t << 6); acc += w[d] * hc[d]; }
#pragma unroll
  for (int off = 32; off; off >>= 1) acc += __shfl_down(acc, off);
  if (lane == 0) av[(b << 8) + half * NN + n] = acc;
}

// ---------------- per-row: adj (fused) + P = W3 @ e_row via bf16 MFMA; e bf16 [c][j] ----------------
template <int FIRST>
__global__ __launch_bounds__(256) void k_plogit_mfma(
    const float* edge, const unsigned short* eP16in, const unsigned short* __restrict__ w3b,
    const float* __restrict__ w_link, const float* __restrict__ av,
    const float* __restrict__ b_link, unsigned short* eP16out, float* __restrict__ adj_out) {
  int b = blockIdx.x >> 7, i = blockIdx.x & 127;
  __shared__ unsigned short eL[128 * 264];       // [j][c], 528B rows (16B-aligned)
  int tid = threadIdx.x;

  if (FIRST) {
    const float* s0 = edge + (size_t)(b * NN + i) * NN * DEE;
    for (int l = tid; l < 4096; l += 256) {
      int j = l >> 5, c0 = (l & 31) * 8;
      float4 v0 = *(const float4*)&s0[(size_t)j * DEE + c0];
      float4 v1 = *(const float4*)&s0[(size_t)j * DEE + c0 + 4];
      unsigned long long p0 = (unsigned long long)f2bf(v0.x) | ((unsigned long long)f2bf(v0.y) << 16)
                            | ((unsigned long long)f2bf(v0.z) << 32) | ((unsigned long long)f2bf(v0.w) << 48);
      unsigned long long p1 = (unsigned long long)f2bf(v1.x) | ((unsigned long long)f2bf(v1.y) << 16)
                            | ((unsigned long long)f2bf(v1.z) << 32) | ((unsigned long long)f2bf(v1.w) << 48);
      *(unsigned long long*)&eL[j * 264 + c0] = p0;
      *(unsigned long long*)&eL[j * 264 + c0 + 4] = p1;
    }
  } else {
    const unsigned short* s0 = eP16in + (size_t)(b * NN + i) * DEE * NN;
#pragma unroll
    for (int t = 0; t < 2; ++t) {
      int blk = tid + t * 256;                   // 512 8x8 blocks
      int c0 = (blk >> 4) * 8, j0 = (blk & 15) * 8;
      short8 rows[8];
#pragma unroll
      for (int cc = 0; cc < 8; ++cc)
        rows[cc] = *(const short8*)&s0[(size_t)(c0 + cc) * NN + j0];
#pragma unroll
      for (int jj = 0; jj < 8; ++jj) {
        short8 o;
#pragma unroll
        for (int cc = 0; cc < 8; ++cc) o[cc] = rows[cc][jj];
        *(short8*)&eL[(j0 + jj) * 264 + c0] = o;
      }
    }
  }
  __syncthreads();

  // logitE per j
  float accLE = 0.f;
  if (tid < NN) {
    const unsigned short* row = &eL[tid * 264];
    for (int c = 0; c < DEE; ++c) accLE += w_link[1024 + c] * bfu(row[c]);
  }

  // MFMA main loop
  const int w = tid >> 6, l = tid & 63;
  const int lm = l & 15, lg = l >> 4;
  f32x4 acc[4][8];
#pragma unroll
  for (int a = 0; a < 4; ++a)
#pragma unroll
    for (int jt = 0; jt < 8; ++jt) acc[a][jt] = (f32x4){0.f, 0.f, 0.f, 0.f};

#pragma unroll
  for (int kk = 0; kk < 8; ++kk) {
    short8 afr[4];
#pragma unroll
    for (int a = 0; a < 4; ++a)
      afr[a] = *(const short8*)&w3b[(size_t)(64 * w + 16 * a + lm) * 256 + 32 * kk + 8 * lg];
#pragma unroll
    for (int jt = 0; jt < 8; ++jt) {
      short8 bfr = *(const short8*)&eL[(16 * jt + lm) * 264 + 32 * kk + 8 * lg];
#pragma unroll
      for (int a = 0; a < 4; ++a)
        acc[a][jt] = __builtin_amdgcn_mfma_f32_16x16x32_bf16(afr[a], bfr, acc[a][jt], 0, 0, 0);
    }
  }

  // epilogue: P bf16 [c][j]
  unsigned short* Pout = eP16out + (size_t)(b * NN + i) * DEE * NN;
#pragma unroll
  for (int a = 0; a < 4; ++a) {
    int rbase = 64 * w + 16 * a + 4 * lg;
#pragma unroll
    for (int jt = 0; jt < 8; ++jt) {
      int j = 16 * jt + lm;
#pragma unroll
      for (int q = 0; q < 4; ++q)
        Pout[(size_t)(rbase + q) * NN + j] = f2bf(acc[a][jt][q]);
    }
  }
  if (tid < NN) {
    float x = av[(b << 8) + NN + i] + av[(b << 8) + tid] + accLE + b_link[0];
    adj_out[((size_t)b * NN + i) * NN + tid] = sigmf(x);
  }
}

// ---------------- merged W@h kernel (R9 scalar, PROVEN) ----------------
__global__ __launch_bounds__(256) void k_wh3(const float* __restrict__ w_hh, const float* __restrict__ w_msg,
                                             const float* __restrict__ b_hh, const float* __restrict__ b_msg,
                                             const float* __restrict__ h, float* __restrict__ GHo,
                                             float* __restrict__ Uo, float* __restrict__ Go) {
  int bx = blockIdx.x, b = blockIdx.y;
  const float* W; const float* bias; float* out; int ldw, R, r0;
  if (bx < 96)       { W = w_hh;        ldw = 512;  R = 1536; bias = b_hh;   out = GHo; r0 = bx * 16; }
  else if (bx < 112) { W = w_msg;       ldw = 1280; R = 256;  bias = b_msg;  out = Uo;  r0 = (bx - 96) * 16; }
  else               { W = w_msg + 512; ldw = 1280; R = 256;  bias = nullptr; out = Go; r0 = (bx - 112) * 16; }
  __shared__ float hT[128][129];
  __shared__ float wT[16][129];
  __shared__ float outT[16][129];
  int tid = threadIdx.x;
  int n = tid & 127, rr = tid >> 7;
  float acc8[8] = {0, 0, 0, 0, 0, 0, 0, 0};
  for (int dc = 0; dc < DVV; dc += 128) {
    if (dc) __syncthreads();
    for (int l = tid * 4; l < 16384; l += 1024) {
      int nn = l >> 7, d = l & 127;
      float4 v = *(const float4*)&h[((size_t)(b << 7) + nn) * DVV + dc + d];
      hT[d + 0][nn] = v.x; hT[d + 1][nn] = v.y; hT[d + 2][nn] = v.z; hT[d + 3][nn] = v.w;
    }
    for (int l = tid; l < 2048; l += 256) {
      int r = l >> 7, d = l & 127;
      wT[r][d] = W[(size_t)(r0 + r) * ldw + dc + d];
    }
    __syncthreads();
    for (int d = 0; d < 128; ++d) {
      float hval = hT[d][n];
#pragma unroll
      for (int r8 = 0; r8 < 8; ++r8) acc8[r8] += wT[rr * 8 + r8][d] * hval;
    }
  }
#pragma unroll
  for (int r8 = 0; r8 < 8; ++r8) {
    int r = rr * 8 + r8;
    outT[r][n] = acc8[r8] + (bias ? bias[r0 + r] : 0.0f);
  }
  __syncthreads();
  int n2 = tid >> 1, q = tid & 1;
  size_t base = ((size_t)(b << 7) + n2) * R + r0 + q * 8;
  float4 o0; o0.x = outT[q * 8 + 0][n2]; o0.y = outT[q * 8 + 1][n2]; o0.z = outT[q * 8 + 2][n2]; o0.w = outT[q * 8 + 3][n2];
  float4 o1; o1.x = outT[q * 8 + 4][n2]; o1.y = outT[q * 8 + 5][n2]; o1.z = outT[q * 8 + 6][n2]; o1.w = outT[q * 8 + 7][n2];
  *(float4*)&out[base] = o0;
  *(float4*)&out[base + 4] = o1;
}

// ---------------- distributed scan: R13 protocol + early prefetch (R14, PROVEN) ----------------
template <int WRITE_E>
__global__ __launch_bounds__(256) void k_scan14(
    unsigned short* eP16, const float* __restrict__ adj, const float* __restrict__ GH,
    const float* __restrict__ U, const float* __restrict__ Gini, float* __restrict__ h,
    unsigned short* __restrict__ hb, const float* __restrict__ w_ih,
    const float* __restrict__ b_ih, const float* __restrict__ w_msg,
    float* __restrict__ gi, unsigned* __restrict__ flags, int kround) {
  const int s = blockIdx.x, b = blockIdx.y, tid = threadIdx.x;
  __shared__ float wihL[16 * 1540];
  __shared__ __align__(16) float w2L[16 * 520];
  __shared__ __align__(16) float GL[16 * 132];
  __shared__ float hnL[DVV];
  __shared__ float msL[16];

  for (int l = tid; l < 1536 * 16; l += 256) {
    int r = l >> 4, c = l & 15;
    wihL[c * 1540 + r] = w_ih[(size_t)r * 256 + 16 * s + c];
  }
  for (int l = tid; l < 16 * 128; l += 256) {
    int c = l >> 7, d4 = (l & 127) * 4;
    *(float4*)&w2L[c * 520 + d4] = *(const float4*)&w_msg[(size_t)(16 * s + c) * 1280 + 512 + d4];
  }
  for (int l = tid; l < 2048; l += 256) {
    int c = l & 15, j = l >> 4;
    GL[c * 132 + j] = Gini[((size_t)b * NN + j) * DEE + 16 * s + c];
  }
  float bi0 = b_ih[tid], bi1 = b_ih[tid + 256];
  float bi2 = b_ih[512 + tid], bi3 = b_ih[768 + tid];
  float bi4 = b_ih[1024 + tid], bi5 = b_ih[1280 + tid];

  const int c_loc = tid >> 4, jg = tid & 15, j0 = jg << 3;

  short8 Pv; float4 A0, A1; float uu;
  float hv0, hv1, ghr0, ghr1, ghz0, ghz1, ghn0, ghn1;
  {
    size_t rE = ((size_t)(b * NN + 0) * DEE + 16 * s + c_loc) * NN + j0;
    Pv = *(const short8*)&eP16[rE];
    size_t rA = (size_t)(b * NN + 0) * NN + j0;
    A0 = *(const float4*)&adj[rA]; A1 = *(const float4*)&adj[rA + 4];
    uu = U[(size_t)(b * NN + 0) * DEE + 16 * s + c_loc];
    size_t rH = (size_t)(b * NN + 0) * DVV;
    hv0 = h[rH + tid]; hv1 = h[rH + tid + 256];
    size_t rG = (size_t)(b * NN + 0) * 1536;
    ghr0 = GH[rG + tid]; ghr1 = GH[rG + tid + 256];
    ghz0 = GH[rG + 512 + tid]; ghz1 = GH[rG + 768 + tid];
    ghn0 = GH[rG + 1024 + tid]; ghn1 = GH[rG + 1280 + tid];
  }

  for (int i = 0; i < NN; ++i) {
    int g = kround * NN + i;
    float* giA = gi + (size_t)(g % 3) * GISLOT + (size_t)b * 1536;
    float* giZ = gi + (size_t)((g + 1) % 3) * GISLOT + (size_t)b * 1536;
    __syncthreads();   // (1)

    // ---- Phase A (uses prefetched Pv/A0/A1/uu) ----
    float acc;
    {
      const float* gl = &GL[c_loc * 132 + j0];
      float4 g0 = *(const float4*)&gl[0];
      float4 g1 = *(const float4*)&gl[4];
      float m0 = fmaxf(uu + g0.x + bfu((unsigned short)Pv[0]), 0.f);
      float m1 = fmaxf(uu + g0.y + bfu((unsigned short)Pv[1]), 0.f);
      float m2 = fmaxf(uu + g0.z + bfu((unsigned short)Pv[2]), 0.f);
      float m3 = fmaxf(uu + g0.w + bfu((unsigned short)Pv[3]), 0.f);
      float m4 = fmaxf(uu + g1.x + bfu((unsigned short)Pv[4]), 0.f);
      float m5 = fmaxf(uu + g1.y + bfu((unsigned short)Pv[5]), 0.f);
      float m6 = fmaxf(uu + g1.z + bfu((unsigned short)Pv[6]), 0.f);
      float m7 = fmaxf(uu + g1.w + bfu((unsigned short)Pv[7]), 0.f);
      acc = A0.x * m0 + A0.y * m1 + A0.z * m2 + A0.w * m3
          + A1.x * m4 + A1.y * m5 + A1.z * m6 + A1.w * m7;
      if (WRITE_E) {
        size_t rE = ((size_t)(b * NN + i) * DEE + 16 * s + c_loc) * NN + j0;
        short8 mw;
        mw[0] = (short)f2bf(m0); mw[1] = (short)f2bf(m1); mw[2] = (short)f2bf(m2); mw[3] = (short)f2bf(m3);
        mw[4] = (short)f2bf(m4); mw[5] = (short)f2bf(m5); mw[6] = (short)f2bf(m6); mw[7] = (short)f2bf(m7);
        *(short8*)&eP16[rE] = mw;
      }
    }
    acc += __shfl_down(acc, 8);
    acc += __shfl_down(acc, 4);
    acc += __shfl_down(acc, 2);
    acc += __shfl_down(acc, 1);
    if (jg == 0) msL[c_loc] = acc;
    __syncthreads();   // (2)

    // ---- Phase B: atomicAdd into slot g%3; zero slot (g+1)%3 ----
    {
      float ms[16];
#pragma unroll
      for (int c = 0; c < 16; ++c) ms[c] = msL[c];
#pragma unroll
      for (int u = 0; u < 6; ++u) {
        int r = tid + (u << 8);
        float pa = 0.f;
#pragma unroll
        for (int c = 0; c < 16; ++c) pa += wihL[c * 1540 + r] * ms[c];
        (void)__hip_atomic_fetch_add(&giA[r], pa, __ATOMIC_RELAXED, __HIP_MEMORY_SCOPE_SYSTEM);
      }
      if (tid < 96)
        __hip_atomic_store(&giZ[96 * s + tid], 0.f, __ATOMIC_RELAXED, __HIP_MEMORY_SCOPE_SYSTEM);
    }

    // ---- barrier: drain atomics -> flag -> PREFETCH(i+1) -> poll ----
    unsigned tgt = (unsigned)(g + 1);
    __syncthreads();   // (3) drains atomics + zero stores
    if (tid == 0)
      __hip_atomic_store(&flags[(((b << 4) + s) << 5)], tgt, __ATOMIC_RELAXED,
                         __HIP_MEMORY_SCOPE_SYSTEM);
    // prefetch for i+1, issued BEFORE the poll so latency hides under
    // poll + gi loads + GRU. Reads drain at sync(5), which precedes our
    // flag(i+1), which precedes any step-(i+1) writer.
    float t_hv0, t_hv1, t_ghr0, t_ghr1, t_ghz0, t_ghz1, t_ghn0, t_ghn1;
    {
      int in = (i < NN - 1) ? i + 1 : NN - 1;
      size_t rE = ((size_t)(b * NN + in) * DEE + 16 * s + c_loc) * NN + j0;
      Pv = *(const short8*)&eP16[rE];
      size_t rA = (size_t)(b * NN + in) * NN + j0;
      A0 = *(const float4*)&adj[rA]; A1 = *(const float4*)&adj[rA + 4];
      uu = U[(size_t)(b * NN + in) * DEE + 16 * s + c_loc];
      size_t rH = (size_t)(b * NN + in) * DVV;
      t_hv0 = h[rH + tid]; t_hv1 = h[rH + tid + 256];
      size_t rG = (size_t)(b * NN + in) * 1536;
      t_ghr0 = GH[rG + tid]; t_ghr1 = GH[rG + tid + 256];
      t_ghz0 = GH[rG + 512 + tid]; t_ghz1 = GH[rG + 768 + tid];
      t_ghn0 = GH[rG + 1024 + tid]; t_ghn1 = GH[rG + 1280 + tid];
    }
    if (tid < 64) {
      unsigned* fp = &flags[(((b << 4) + (tid & 15)) << 5)];
      for (;;) {
        unsigned v = __hip_atomic_load(fp, __ATOMIC_RELAXED, __HIP_MEMORY_SCOPE_SYSTEM);
        if (!__any(v < tgt)) break;
        __builtin_amdgcn_s_sleep(1);
      }
    }
    __syncthreads();   // (4)

    // ---- GRU: 6 sc1 loads of summed gi + bias (uses OLD hv/gh regs) ----
    {
      float sr0 = bi0 + __hip_atomic_load(&giA[tid],        __ATOMIC_RELAXED, __HIP_MEMORY_SCOPE_SYSTEM);
      float sr1 = bi1 + __hip_atomic_load(&giA[tid + 256],  __ATOMIC_RELAXED, __HIP_MEMORY_SCOPE_SYSTEM);
      float sz0 = bi2 + __hip_atomic_load(&giA[512 + tid],  __ATOMIC_RELAXED, __HIP_MEMORY_SCOPE_SYSTEM);
      float sz1 = bi3 + __hip_atomic_load(&giA[768 + tid],  __ATOMIC_RELAXED, __HIP_MEMORY_SCOPE_SYSTEM);
      float sn0 = bi4 + __hip_atomic_load(&giA[1024 + tid], __ATOMIC_RELAXED, __HIP_MEMORY_SCOPE_SYSTEM);
      float sn1 = bi5 + __hip_atomic_load(&giA[1280 + tid], __ATOMIC_RELAXED, __HIP_MEMORY_SCOPE_SYSTEM);
      float rg0 = sigmf(sr0 + ghr0), rg1 = sigmf(sr1 + ghr1);
      float z0 = sigmf(sz0 + ghz0),  z1 = sigmf(sz1 + ghz1);
      float nv0 = tanhf_fast(sn0 + rg0 * ghn0);
      float nv1 = tanhf_fast(sn1 + rg1 * ghn1);
      float hn0 = (1.f - z0) * nv0 + z0 * hv0;
      float hn1 = (1.f - z1) * nv1 + z1 * hv1;
      hnL[tid] = hn0; hnL[tid + 256] = hn1;
      size_t rH = (size_t)(b * NN + i) * DVV;
      if ((tid >> 5) == s)         { h[rH + tid] = hn0;       hb[rH + tid] = f2bf(hn0); }
      if (((tid + 256) >> 5) == s) { h[rH + tid + 256] = hn1; hb[rH + tid + 256] = f2bf(hn1); }
    }
    // commit prefetched h/GH for next step
    hv0 = t_hv0; hv1 = t_hv1;
    ghr0 = t_ghr0; ghr1 = t_ghr1;
    ghz0 = t_ghz0; ghz1 = t_ghz1;
    ghn0 = t_ghn0; ghn1 = t_ghn1;
    __syncthreads();   // (5)

    // ---- Phase C ----
    {
      int cw = tid >> 4, dg = tid & 15;
      float acc2 = 0.f;
#pragma unroll
      for (int it = 0; it < 32; ++it) {
        int d = dg + (it << 4);
        acc2 += w2L[cw * 520 + d] * hnL[d];
      }
      acc2 += __shfl_down(acc2, 8);
      acc2 += __shfl_down(acc2, 4);
      acc2 += __shfl_down(acc2, 2);
      acc2 += __shfl_down(acc2, 1);
      if (dg == 0) GL[cw * 132 + i] = acc2;
    }
  }
}

// ---------------- labels ----------------
__global__ __launch_bounds__(128) void k_labels(const float* __restrict__ h, const float* __restrict__ w_ro,
                                                const float* __restrict__ b_ro, float* __restrict__ out) {
  int b = blockIdx.x >> 7, n = blockIdx.x & 127;
  __shared__ __align__(16) float hr[512];
  int tid = threadIdx.x;
  *(float4*)&hr[tid * 4] = *(const float4*)&h[(size_t)((b << 7) + n) * DVV + tid * 4];
  __syncthreads();
  if (tid < NCC) {
    const float* w = w_ro + (size_t)tid * DVV;
    float acc = b_ro[tid];
    for (int d = 0; d < DVV; d += 4) {
      float4 wv = *(const float4*)&w[d];
      acc += wv.x * hr[d] + wv.y * hr[d + 1] + wv.z * hr[d + 2] + wv.w * hr[d + 3];
    }
    out[(size_t)((b << 7) + n) * NCC + tid] = acc;
  }
}

extern "C" void kernel_launch(void* const* d_in, const int* in_sizes, int n_in,
                              void* d_out, int out_size, void* d_ws, size_t ws_size,
                              hipStream_t stream) {
  const float* edge   = (const float*)d_in[0];
  const float* node   = (const float*)d_in[1];
  const float* w_link = (const float*)d_in[6];
  const float* b_link = (const float*)d_in[7];
  const float* w_msg  = (const float*)d_in[8];
  const float* b_msg  = (const float*)d_in[9];
  const float* w_ih   = (const float*)d_in[10];
  const float* w_hh   = (const float*)d_in[11];
  const float* b_ih   = (const float*)d_in[12];
  const float* b_hh   = (const float*)d_in[13];
  const float* w_ro   = (const float*)d_in[14];
  const float* b_ro   = (const float*)d_in[15];
  float* out = (float*)d_out;
  float* ws  = (float*)d_ws;

  unsigned short* eP16 = (unsigned short*)ws;               // 33,554,432 ushorts
  unsigned short* hb   = (unsigned short*)(ws + 21000000);  //   524,288 ushorts
  float* h_buf  = ws + 33554432ull;        //    524,288  (B,N,DV)
  float* GH_buf = h_buf + 524288;          //  1,572,864  (B,N,1536)
  float* U_buf  = GH_buf + 1572864;        //    262,144  (B,N,256)
  float* G_buf  = U_buf + 262144;          //    262,144  (B,N,256)
  float* lE_buf = G_buf + 262144;          //    131,072  (reused: w3b)
  float* av_buf = lE_buf + 131072;         //      2,048  (B,2,N)
  float* gi_buf = av_buf + 2048;           //     36,864  (3 slots x B x 1536)
  unsigned* flags = (unsigned*)(gi_buf + 3 * GISLOT);  // 4096 u32
  unsigned short* w3b = (unsigned short*)lE_buf;
  size_t need_bytes = 36710304ull * 4ull;
  if (ws_size < need_bytes) return;

  hipMemsetAsync(gi_buf, 0, (3 * GISLOT + 4096) * sizeof(float), stream);
  k_copy<<<512, 256, 0, stream>>>(node, h_buf, hb);
  k_cvtw<<<256, 256, 0, stream>>>(w_msg, w3b);

  for (int k = 0; k < 3; ++k) {
    k_av<<<1024, 128, 0, stream>>>(h_buf, w_link, av_buf);
    if (k == 0) k_plogit_mfma<1><<<1024, 256, 0, stream>>>(edge, eP16, w3b, w_link, av_buf, b_link, eP16, out);
    else        k_plogit_mfma<0><<<1024, 256, 0, stream>>>(edge, eP16, w3b, w_link, av_buf, b_link, eP16, out);
    k_wh3<<<dim3(128, 8), 256, 0, stream>>>(w_hh, w_msg, b_hh, b_msg, h_buf, GH_buf, U_buf, G_buf);
    if (k < 2) k_scan14<1><<<dim3(SB, NB), 256, 0, stream>>>(eP16, out, GH_buf, U_buf, G_buf, h_buf, hb,
                                                             w_ih, b_ih, w_msg, gi_buf, flags, k);
    else       k_scan14<0><<<dim3(SB, NB), 256, 0, stream>>>(eP16, out, GH_buf, U_buf, G_buf, h_buf, hb,
                                                             w_ih, b_ih, w_msg, gi_buf, flags, k);
  }
  k_labels<<<1024, 128, 0, stream>>>(h_buf, w_ro, b_ro, out + 131072);
}